// Round 1
// baseline (173.176 us; speedup 1.0000x reference)
//
#include <hip/hip_runtime.h>
#include <stdint.h>

// DepthAwareConv2d: out = conv2d(x * depth, weight, pad=1) + bias
// (depth is channel-independent, so the depth-modulated im2col GEMM factors
//  into a plain 3x3 conv of xd = x*depth).
//
// Pipeline (all on `stream`, graph-capture safe):
//   1) hipMemsetAsync: zero the padded xd buffer (zeroes the halo)
//   2) prep_xd : xd[n][y+1][x+1][c] = bf16(x[n,c,y,x]*depth[n,y,x])  (padded NHWC)
//   3) prep_wt : wt[o][tap*128+c]   = bf16(weight[o,c,ti,tj])        (k = tap*128+c)
//   4) conv_mfma: implicit GEMM  M=O=256, N=4*128*128, K=1152
//      128x128 tile, BK=32, mfma_f32_16x16x32_bf16, global_load_lds x16B (m97 shape)

#define C_IN 128
#define O_OUT 256
#define HW 128
#define NB 4
#define PADW 130

#define XD_ELEMS ((size_t)NB * PADW * PADW * C_IN)
#define XD_BYTES (XD_ELEMS * 2)          // 17,305,600 B
#define WT_ELEMS ((size_t)O_OUT * C_IN * 9)
#define WT_BYTES (WT_ELEMS * 2)          // 589,824 B

typedef __attribute__((ext_vector_type(8))) short short8;  // 8 bf16 (4 VGPRs)
typedef __attribute__((ext_vector_type(4))) float f32x4;

__device__ __forceinline__ unsigned f2bf_bits(float f) {
  unsigned u = __builtin_bit_cast(unsigned, f);
  return (u + 0x7fffu + ((u >> 16) & 1u)) >> 16;   // RNE, inputs finite
}

__device__ __forceinline__ void async_load16(const void* g, void* l) {
  __builtin_amdgcn_global_load_lds(
      (__attribute__((address_space(1))) void*)g,
      (__attribute__((address_space(3))) void*)l, 16, 0, 0);
}

// ---- prep: xd = bf16(x*depth), NCHW -> padded NHWC -------------------------
// One block per (n,y) image row. Reads coalesced along x (4B/lane, contiguous);
// writes are 4B (c-pair) at 256B pixel stride — L2 write-merges lines since the
// whole 128-channel row is produced by the block.
__global__ void prep_xd(const float* __restrict__ x,
                        const float* __restrict__ depth,
                        unsigned* __restrict__ xd) {
  const int R = blockIdx.x;          // n*128 + y
  const int n = R >> 7, y = R & 127;
  const int tid = threadIdx.x;
  const int xc = tid & 127;
  const int ch = (tid >> 7) << 6;    // 0 or 64
  const float dv = depth[((size_t)n * HW + y) * HW + xc];
  const float* xcol = x + ((size_t)n * C_IN * HW + y) * HW + xc;  // + c*HW*HW
  unsigned* orow = xd +
      ((size_t)(n * PADW + y + 1) * PADW + (xc + 1)) * (C_IN / 2);
#pragma unroll 4
  for (int ci = 0; ci < 32; ++ci) {
    const int c = ch + ci * 2;
    const float v0 = xcol[(size_t)c * HW * HW] * dv;
    const float v1 = xcol[(size_t)(c + 1) * HW * HW] * dv;
    orow[(ch >> 1) + ci] = f2bf_bits(v0) | (f2bf_bits(v1) << 16);
  }
}

// ---- prep: weight (O,C,3,3) fp32 -> wt[o][tap*128+c] bf16 ------------------
__global__ void prep_wt(const float* __restrict__ w, short* __restrict__ wt) {
  const int gid = blockIdx.x * 256 + threadIdx.x;
  if (gid >= (int)WT_ELEMS) return;
  const int c = gid & 127;
  const int tap = (gid >> 7) % 9;
  const int o = gid / (9 * 128);
  wt[gid] = (short)f2bf_bits(w[((size_t)o * C_IN + c) * 9 + tap]);
}

// ---- main MFMA implicit-GEMM conv ------------------------------------------
// Block: 256 threads (4 waves, 2x2 wave grid), tile 128(o) x 128(x of one row).
// K loop: kt = (tap, c-chunk), 36 steps of BK=32.
__global__ __launch_bounds__(256) void conv_mfma(
    const short* __restrict__ xd, const short* __restrict__ wt,
    const float* __restrict__ bias, float* __restrict__ out) {
  __shared__ short lds[8192];
  short* Ws = lds;          // [128 o][32 k] rows of 64B, k-contiguous
  short* Xs = lds + 4096;   // [128 p][32 k]

  const int tid = threadIdx.x;
  const int R = blockIdx.x;             // n*128 + y
  const int n = R >> 7, y = R & 127;
  const int o0 = blockIdx.y << 7;
  const int lane = tid & 63;
  const int wave = tid >> 6;
  const int wm = wave & 1, wn = wave >> 1;
  const int ln = lane & 15, q = lane >> 4;

  // staging: chunk = tid (+256), row = chunk>>2 (o or pixel), part = chunk&3
  const int row0 = tid >> 2;            // 0..63
  const int part = tid & 3;

  const short* wg0 = wt + (size_t)(o0 + row0) * 1152 + part * 8;
  const short* wg1 = wt + (size_t)(o0 + row0 + 64) * 1152 + part * 8;
  const short* xg0 = xd + ((size_t)(n * PADW + y) * PADW + row0) * C_IN + part * 8;
  const short* xg1 = xg0 + (size_t)64 * C_IN;

  short* lw0 = Ws + tid * 8;
  short* lw1 = Ws + 2048 + tid * 8;
  short* lx0 = Xs + tid * 8;
  short* lx1 = Xs + 2048 + tid * 8;

  f32x4 acc[4][4] = {};

  for (int kt = 0; kt < 36; ++kt) {
    const int tap = kt >> 2;
    const int cc = kt & 3;
    const int ti = tap / 3;             // uniform scalar math
    const int tj = tap - ti * 3;
    const int wofs = kt << 5;                               // tap*128 + cc*32
    const int xofs = ((ti * PADW + tj) << 7) + (cc << 5);   // shorts

    async_load16(wg0 + wofs, lw0);
    async_load16(wg1 + wofs, lw1);
    async_load16(xg0 + xofs, lx0);
    async_load16(xg1 + xofs, lx1);

    asm volatile("s_waitcnt vmcnt(0)" ::: "memory");
    __syncthreads();

    short8 a[4], b[4];
#pragma unroll
    for (int t = 0; t < 4; ++t)
      a[t] = *(const short8*)(Ws + (((wm << 6) + (t << 4) + ln) << 5) + q * 8);
#pragma unroll
    for (int u = 0; u < 4; ++u)
      b[u] = *(const short8*)(Xs + (((wn << 6) + (u << 4) + ln) << 5) + q * 8);
#pragma unroll
    for (int t = 0; t < 4; ++t)
#pragma unroll
      for (int u = 0; u < 4; ++u)
        acc[t][u] =
            __builtin_amdgcn_mfma_f32_16x16x32_bf16(a[t], b[u], acc[t][u], 0, 0, 0);

    __syncthreads();
  }

  // epilogue: D layout col=lane&15 (x), row=q*4+r (o)
#pragma unroll
  for (int t = 0; t < 4; ++t) {
    const int ob = o0 + (wm << 6) + (t << 4) + (q << 2);
#pragma unroll
    for (int u = 0; u < 4; ++u) {
      const int xcol = (wn << 6) + (u << 4) + ln;
#pragma unroll
      for (int r = 0; r < 4; ++r) {
        const int o = ob + r;
        out[(((size_t)n * O_OUT + o) * HW + y) * HW + xcol] = acc[t][u][r] + bias[o];
      }
    }
  }
}

// ---- fallback (only if ws_size is too small): naive direct conv ------------
__global__ void conv_naive(const float* __restrict__ x,
                           const float* __restrict__ depth,
                           const float* __restrict__ w,
                           const float* __restrict__ bias,
                           float* __restrict__ out) {
  const int gid = blockIdx.x * 256 + threadIdx.x;
  if (gid >= NB * O_OUT * HW * HW) return;
  const int xc = gid & 127;
  const int y = (gid >> 7) & 127;
  const int o = (gid >> 14) & 255;
  const int n = gid >> 22;
  float s = bias[o];
  for (int c = 0; c < C_IN; ++c)
    for (int i = 0; i < 3; ++i) {
      const int yy = y + i - 1;
      if (yy < 0 || yy >= HW) continue;
      for (int j = 0; j < 3; ++j) {
        const int xx = xc + j - 1;
        if (xx < 0 || xx >= HW) continue;
        s += w[((o * C_IN + c) * 3 + i) * 3 + j] *
             x[(((size_t)n * C_IN + c) * HW + yy) * HW + xx] *
             depth[((size_t)n * HW + yy) * HW + xx];
      }
    }
  out[gid] = s;
}

extern "C" void kernel_launch(void* const* d_in, const int* in_sizes, int n_in,
                              void* d_out, int out_size, void* d_ws, size_t ws_size,
                              hipStream_t stream) {
  const float* x = (const float*)d_in[0];
  const float* depth = (const float*)d_in[1];
  // d_in[2] = camera_params (unused by reference)
  const float* weight = (const float*)d_in[3];
  const float* bias = (const float*)d_in[4];
  float* out = (float*)d_out;

  const size_t need = XD_BYTES + WT_BYTES;
  if (ws_size < need) {
    conv_naive<<<(NB * O_OUT * HW * HW + 255) / 256, 256, 0, stream>>>(
        x, depth, weight, bias, out);
    return;
  }

  short* xd = (short*)d_ws;
  short* wt = (short*)((char*)d_ws + XD_BYTES);

  hipMemsetAsync(d_ws, 0, XD_BYTES, stream);   // zero halo (ws re-poisoned per call)
  prep_xd<<<NB * HW, 256, 0, stream>>>(x, depth, (unsigned*)xd);
  prep_wt<<<(int)((WT_ELEMS + 255) / 256), 256, 0, stream>>>(weight, wt);
  conv_mfma<<<dim3(NB * HW, 2), 256, 0, stream>>>(xd, wt, bias, out);
}

// Round 2
// 156.961 us; speedup vs baseline: 1.1033x; 1.1033x over previous
//
#include <hip/hip_runtime.h>
#include <stdint.h>

// DepthAwareConv2d: out = conv2d(x * depth, weight, pad=1) + bias
// (depth is channel-independent, so the depth-modulated im2col GEMM factors
//  into a plain 3x3 conv of xd = x*depth).
//
// R2: (a) conv K-loop restructured to single-barrier double-buffered pipeline
//     (prefetch kt+1 after barrier -> load latency hidden behind MFMA of kt),
//     (b) XOR chunk-swizzle to cut ds_read_b128 bank conflicts,
//     (c) prep_xd via LDS transpose with fused halo zeroing (memset deleted).

#define C_IN 128
#define O_OUT 256
#define HW 128
#define NB 4
#define PADW 130

#define XD_ELEMS ((size_t)NB * PADW * PADW * C_IN)
#define XD_BYTES (XD_ELEMS * 2)          // 17,305,600 B
#define WT_ELEMS ((size_t)O_OUT * C_IN * 9)
#define WT_BYTES (WT_ELEMS * 2)          // 589,824 B

typedef __attribute__((ext_vector_type(8))) short short8;  // 8 bf16 (4 VGPRs)
typedef __attribute__((ext_vector_type(4))) float f32x4;
typedef __attribute__((ext_vector_type(4))) unsigned uint4v;

__device__ __forceinline__ unsigned f2bf_bits(float f) {
  unsigned u = __builtin_bit_cast(unsigned, f);
  return (u + 0x7fffu + ((u >> 16) & 1u)) >> 16;   // RNE, inputs finite
}

__device__ __forceinline__ void async_load16(const void* g, void* l) {
  __builtin_amdgcn_global_load_lds(
      (__attribute__((address_space(1))) void*)g,
      (__attribute__((address_space(3))) void*)l, 16, 0, 0);
}

// ---- prep: xd = bf16(x*depth), NCHW -> padded NHWC, halo fused -------------
// Blocks 0..511: one per (n,y) row. Phase 1: coalesced float2 reads along x,
// transpose into LDS (pixel-major, stride 130 shorts). Phase 2: coalesced
// dword writes of the NHWC row. Edge pixels (x=0,129) zeroed by tid<128.
// Blocks 512..515: zero halo rows 0 and 129 of image n.
__global__ __launch_bounds__(256) void prep_xd(const float* __restrict__ x,
                                               const float* __restrict__ depth,
                                               short* __restrict__ xd) {
  __shared__ short s[128 * 130];   // [pixel x][channel c], stride 130

  const int R = blockIdx.x;
  if (R >= NB * HW) {                       // halo-row zero blocks
    const int n = R - NB * HW;
    uint4v* base0 = (uint4v*)(xd + (size_t)n * PADW * PADW * C_IN);
    uint4v* base1 = (uint4v*)(xd + ((size_t)n * PADW + (PADW - 1)) * PADW * C_IN);
    const uint4v z = {0u, 0u, 0u, 0u};
    const int per_row = PADW * C_IN * 2 / 16;   // 2080 uint4 per padded row
    for (int i = threadIdx.x; i < per_row; i += 256) {
      base0[i] = z;
      base1[i] = z;
    }
    return;
  }

  const int n = R >> 7, y = R & 127;
  const int tid = threadIdx.x;
  const int lane = tid & 63;
  const int wave = tid >> 6;

  // zero the two edge pixels of this padded row (x=0 and x=129)
  {
    unsigned* row = (unsigned*)(xd + ((size_t)(n * PADW + y + 1) * PADW) * C_IN);
    if (tid < 64) row[tid] = 0u;                              // pixel 0
    else if (tid < 128) row[(size_t)(PADW - 1) * 64 + (tid - 64)] = 0u;  // pixel 129
  }

  // phase 1: read x (float2, coalesced), scale by depth, transpose into LDS
  typedef __attribute__((ext_vector_type(2))) float f32x2;
  const f32x2 d2 = *(const f32x2*)(depth + ((size_t)n * HW + y) * HW + 2 * lane);
  const float* xrow = x + (((size_t)n * C_IN) * HW + y) * HW + 2 * lane;
#pragma unroll 8
  for (int ci = 0; ci < 32; ++ci) {
    const int c = ci * 4 + wave;
    const f32x2 v = *(const f32x2*)(xrow + (size_t)c * HW * HW);
    s[(2 * lane) * 130 + c] = (short)f2bf_bits(v.x * d2.x);
    s[(2 * lane + 1) * 130 + c] = (short)f2bf_bits(v.y * d2.y);
  }
  __syncthreads();

  // phase 2: coalesced NHWC write (pixels 1..128 of the padded row)
  unsigned* orow = (unsigned*)(xd + ((size_t)(n * PADW + y + 1) * PADW + 1) * C_IN);
#pragma unroll 8
  for (int i = 0; i < 32; ++i) {
    const int flat = tid + i * 256;      // 0..8191 dwords
    const int px = flat >> 6, cp = flat & 63;
    orow[flat] = ((const unsigned*)s)[px * 65 + cp];
  }
}

// ---- prep: weight (O,C,3,3) fp32 -> wt[o][tap*128+c] bf16 ------------------
__global__ void prep_wt(const float* __restrict__ w, short* __restrict__ wt) {
  const int gid = blockIdx.x * 256 + threadIdx.x;
  if (gid >= (int)WT_ELEMS) return;
  const int c = gid & 127;
  const int tap = (gid >> 7) % 9;
  const int o = gid / (9 * 128);
  wt[gid] = (short)f2bf_bits(w[((size_t)o * C_IN + c) * 9 + tap]);
}

// ---- main MFMA implicit-GEMM conv ------------------------------------------
// Block: 256 threads (4 waves, 2x2), tile 128(o) x 128(pixels of one row).
// K = 1152 (tap-major, c within), BK=32, 36 steps.
// Double-buffered LDS (2 x 16 KB); ONE barrier per iteration: prefetch kt+1
// is issued AFTER the barrier, so the compiler's vmcnt(0)-drain before the
// NEXT barrier waits on loads that overlapped a full ds_read+MFMA phase.
// XOR chunk swizzle (chunk ^= row&3) spreads b128 reads over 4 bank-quads.
__global__ __launch_bounds__(256) void conv_mfma(
    const short* __restrict__ xd, const short* __restrict__ wt,
    const float* __restrict__ bias, float* __restrict__ out) {
  __shared__ short lds[16384];   // buf0: W[0,4096) X[4096,8192); buf1: +8192

  const int tid = threadIdx.x;
  const int R = blockIdx.x;             // n*128 + y
  const int n = R >> 7, y = R & 127;
  const int o0 = blockIdx.y << 7;
  const int lane = tid & 63;
  const int wave = tid >> 6;
  const int wm = wave & 1, wn = wave >> 1;
  const int ln = lane & 15, q = lane >> 4;

  // staging: slot tid = (row0, part); slot holds global chunk part^(row0&3)
  const int row0 = tid >> 2;            // 0..63
  const int part = (tid & 3) ^ (row0 & 3);

  const short* wg0 = wt + (size_t)(o0 + row0) * 1152 + part * 8;
  const short* wg1 = wt + (size_t)(o0 + row0 + 64) * 1152 + part * 8;
  const short* xg0 = xd + ((size_t)(n * PADW + y) * PADW + row0) * C_IN + part * 8;
  const short* xg1 = xg0 + (size_t)64 * C_IN;

  f32x4 acc[4][4] = {};

  auto stage = [&](int kt, int bufo) {
    const int tap = kt >> 2;
    const int cc = kt & 3;
    const int ti = tap / 3;
    const int tj = tap - ti * 3;
    const int wofs = kt << 5;                               // shorts
    const int xofs = ((ti * PADW + tj) << 7) + (cc << 5);   // shorts
    short* lb = lds + bufo + tid * 8;
    async_load16(wg0 + wofs, lb);
    async_load16(wg1 + wofs, lb + 2048);
    async_load16(xg0 + xofs, lb + 4096);
    async_load16(xg1 + xofs, lb + 6144);
  };

  stage(0, 0);   // prologue

  const int swz = (ln & 3);   // row&3 of every fragment row this lane touches

  for (int kt = 0; kt < 36; ++kt) {
    __syncthreads();   // compiler emits vmcnt(0) drain: loads(kt) complete

    if (kt + 1 < 36) stage(kt + 1, ((kt + 1) & 1) << 13);

    const short* Ws = lds + ((kt & 1) << 13);
    const short* Xs = Ws + 4096;

    short8 a[4], b[4];
#pragma unroll
    for (int t = 0; t < 4; ++t)
      a[t] = *(const short8*)(Ws + (((wm << 6) + (t << 4) + ln) << 5) +
                              ((q ^ swz) << 3));
#pragma unroll
    for (int u = 0; u < 4; ++u)
      b[u] = *(const short8*)(Xs + (((wn << 6) + (u << 4) + ln) << 5) +
                              ((q ^ swz) << 3));
#pragma unroll
    for (int t = 0; t < 4; ++t)
#pragma unroll
      for (int u = 0; u < 4; ++u)
        acc[t][u] =
            __builtin_amdgcn_mfma_f32_16x16x32_bf16(a[t], b[u], acc[t][u], 0, 0, 0);
  }

  // epilogue: D layout col=lane&15 (pixel), row=q*4+r (o)
#pragma unroll
  for (int t = 0; t < 4; ++t) {
    const int ob = o0 + (wm << 6) + (t << 4) + (q << 2);
#pragma unroll
    for (int u = 0; u < 4; ++u) {
      const int xcol = (wn << 6) + (u << 4) + ln;
#pragma unroll
      for (int r = 0; r < 4; ++r) {
        const int o = ob + r;
        out[(((size_t)n * O_OUT + o) * HW + y) * HW + xcol] = acc[t][u][r] + bias[o];
      }
    }
  }
}

// ---- fallback (only if ws_size is too small): naive direct conv ------------
__global__ void conv_naive(const float* __restrict__ x,
                           const float* __restrict__ depth,
                           const float* __restrict__ w,
                           const float* __restrict__ bias,
                           float* __restrict__ out) {
  const int gid = blockIdx.x * 256 + threadIdx.x;
  if (gid >= NB * O_OUT * HW * HW) return;
  const int xc = gid & 127;
  const int y = (gid >> 7) & 127;
  const int o = (gid >> 14) & 255;
  const int n = gid >> 22;
  float s = bias[o];
  for (int c = 0; c < C_IN; ++c)
    for (int i = 0; i < 3; ++i) {
      const int yy = y + i - 1;
      if (yy < 0 || yy >= HW) continue;
      for (int j = 0; j < 3; ++j) {
        const int xx = xc + j - 1;
        if (xx < 0 || xx >= HW) continue;
        s += w[((o * C_IN + c) * 3 + i) * 3 + j] *
             x[(((size_t)n * C_IN + c) * HW + yy) * HW + xx] *
             depth[((size_t)n * HW + yy) * HW + xx];
      }
    }
  out[gid] = s;
}

extern "C" void kernel_launch(void* const* d_in, const int* in_sizes, int n_in,
                              void* d_out, int out_size, void* d_ws, size_t ws_size,
                              hipStream_t stream) {
  const float* x = (const float*)d_in[0];
  const float* depth = (const float*)d_in[1];
  // d_in[2] = camera_params (unused by reference)
  const float* weight = (const float*)d_in[3];
  const float* bias = (const float*)d_in[4];
  float* out = (float*)d_out;

  const size_t need = XD_BYTES + WT_BYTES;
  if (ws_size < need) {
    conv_naive<<<(NB * O_OUT * HW * HW + 255) / 256, 256, 0, stream>>>(
        x, depth, weight, bias, out);
    return;
  }

  short* xd = (short*)d_ws;
  short* wt = (short*)((char*)d_ws + XD_BYTES);

  prep_xd<<<NB * HW + NB, 256, 0, stream>>>(x, depth, xd);
  prep_wt<<<(int)((WT_ELEMS + 255) / 256), 256, 0, stream>>>(weight, wt);
  conv_mfma<<<dim3(NB * HW, 2), 256, 0, stream>>>(xd, wt, bias, out);
}

// Round 3
// 139.868 us; speedup vs baseline: 1.2381x; 1.1222x over previous
//
#include <hip/hip_runtime.h>
#include <stdint.h>

// DepthAwareConv2d: out = conv2d(x * depth, weight, pad=1) + bias
// (depth is channel-independent, so the depth-modulated im2col GEMM factors
//  into a plain 3x3 conv of xd = x*depth).
//
// R3: conv block tile 128(o) x 256(px) (2 image rows), wave tile 64x128
//     (acc 4x8) -> 25% fewer LDS reads & staged bytes per MFMA, half the
//     barriers per output. Single-barrier double-buffered K-loop kept.
//     XOR swizzle dropped (R2: conflict counter bit-identical -> null).
//     Address math: vector base per site + uniform scalar tap offset;
//     unroll-4 makes buffer parity static (VALU/iter ~16 vs ~66).

#define C_IN 128
#define O_OUT 256
#define HW 128
#define NB 4
#define PADW 130

#define XD_ELEMS ((size_t)NB * PADW * PADW * C_IN)
#define XD_BYTES (XD_ELEMS * 2)          // 17,305,600 B
#define WT_ELEMS ((size_t)O_OUT * C_IN * 9)
#define WT_BYTES (WT_ELEMS * 2)          // 589,824 B

typedef __attribute__((ext_vector_type(8))) short short8;  // 8 bf16 (4 VGPRs)
typedef __attribute__((ext_vector_type(4))) float f32x4;
typedef __attribute__((ext_vector_type(4))) unsigned uint4v;

__device__ __forceinline__ unsigned f2bf_bits(float f) {
  unsigned u = __builtin_bit_cast(unsigned, f);
  return (u + 0x7fffu + ((u >> 16) & 1u)) >> 16;   // RNE, inputs finite
}

__device__ __forceinline__ void async_load16(const void* g, void* l) {
  __builtin_amdgcn_global_load_lds(
      (__attribute__((address_space(1))) void*)g,
      (__attribute__((address_space(3))) void*)l, 16, 0, 0);
}

// ---- prep: xd = bf16(x*depth), NCHW -> padded NHWC, halo fused -------------
// Blocks 0..511: one per (n,y) row. Phase 1: coalesced float2 reads along x,
// transpose into LDS (pixel-major, stride 130 shorts). Phase 2: coalesced
// dword writes of the NHWC row. Edge pixels (x=0,129) zeroed by tid<128.
// Blocks 512..515: zero halo rows 0 and 129 of image n.
__global__ __launch_bounds__(256) void prep_xd(const float* __restrict__ x,
                                               const float* __restrict__ depth,
                                               short* __restrict__ xd) {
  __shared__ short s[128 * 130];   // [pixel x][channel c], stride 130

  const int R = blockIdx.x;
  if (R >= NB * HW) {                       // halo-row zero blocks
    const int n = R - NB * HW;
    uint4v* base0 = (uint4v*)(xd + (size_t)n * PADW * PADW * C_IN);
    uint4v* base1 = (uint4v*)(xd + ((size_t)n * PADW + (PADW - 1)) * PADW * C_IN);
    const uint4v z = {0u, 0u, 0u, 0u};
    const int per_row = PADW * C_IN * 2 / 16;   // 2080 uint4 per padded row
    for (int i = threadIdx.x; i < per_row; i += 256) {
      base0[i] = z;
      base1[i] = z;
    }
    return;
  }

  const int n = R >> 7, y = R & 127;
  const int tid = threadIdx.x;
  const int lane = tid & 63;
  const int wave = tid >> 6;

  // zero the two edge pixels of this padded row (x=0 and x=129)
  {
    unsigned* row = (unsigned*)(xd + ((size_t)(n * PADW + y + 1) * PADW) * C_IN);
    if (tid < 64) row[tid] = 0u;                              // pixel 0
    else if (tid < 128) row[(size_t)(PADW - 1) * 64 + (tid - 64)] = 0u;  // pixel 129
  }

  // phase 1: read x (float2, coalesced), scale by depth, transpose into LDS
  typedef __attribute__((ext_vector_type(2))) float f32x2;
  const f32x2 d2 = *(const f32x2*)(depth + ((size_t)n * HW + y) * HW + 2 * lane);
  const float* xrow = x + (((size_t)n * C_IN) * HW + y) * HW + 2 * lane;
#pragma unroll 8
  for (int ci = 0; ci < 32; ++ci) {
    const int c = ci * 4 + wave;
    const f32x2 v = *(const f32x2*)(xrow + (size_t)c * HW * HW);
    s[(2 * lane) * 130 + c] = (short)f2bf_bits(v.x * d2.x);
    s[(2 * lane + 1) * 130 + c] = (short)f2bf_bits(v.y * d2.y);
  }
  __syncthreads();

  // phase 2: coalesced NHWC write (pixels 1..128 of the padded row)
  unsigned* orow = (unsigned*)(xd + ((size_t)(n * PADW + y + 1) * PADW + 1) * C_IN);
#pragma unroll 8
  for (int i = 0; i < 32; ++i) {
    const int flat = tid + i * 256;      // 0..8191 dwords
    const int px = flat >> 6, cp = flat & 63;
    orow[flat] = ((const unsigned*)s)[px * 65 + cp];
  }
}

// ---- prep: weight (O,C,3,3) fp32 -> wt[o][tap*128+c] bf16 ------------------
__global__ void prep_wt(const float* __restrict__ w, short* __restrict__ wt) {
  const int gid = blockIdx.x * 256 + threadIdx.x;
  if (gid >= (int)WT_ELEMS) return;
  const int c = gid & 127;
  const int tap = (gid >> 7) % 9;
  const int o = gid / (9 * 128);
  wt[gid] = (short)f2bf_bits(w[((size_t)o * C_IN + c) * 9 + tap]);
}

// ---- main MFMA implicit-GEMM conv ------------------------------------------
// Block: 256 threads (4 waves, 2x2), tile 128(o) x 256(px = 2 image rows).
// Wave tile 64(o) x 128(px): acc 4x8 frags (128 VGPR). K = 1152, BK=32.
// LDS per buffer: Ws 128x32 (8 KB) + Xs 256x32 (16 KB) = 24 KB, x2 buffers.
// One barrier/iter; prefetch kt+1 issued after the barrier (R2 pipeline).
__global__ __launch_bounds__(256, 2) void conv_mfma(
    const short* __restrict__ xd, const short* __restrict__ wt,
    const float* __restrict__ bias, float* __restrict__ out) {
  __shared__ short lds[24576];   // buf0: [0,12288), buf1: [12288,24576)

  const int tid = threadIdx.x;
  const int bx = blockIdx.x;            // n*64 + ypair
  const int n = bx >> 6;
  const int y = (bx & 63) << 1;         // first of two output rows
  const int o0 = blockIdx.y << 7;
  const int lane = tid & 63;
  const int wave = tid >> 6;
  const int wm = wave & 1, wn = wave >> 1;
  const int ln = lane & 15, q = lane >> 4;

  // staging: slot tid = (row0 = tid>>2, part = tid&3), 16 B per slot
  const int row0 = tid >> 2;            // 0..63
  const int part = tid & 3;

  const short* wg0 = wt + (size_t)(o0 + row0) * 1152 + part * 8;
  const short* wg1 = wg0 + (size_t)64 * 1152;
  // X bases: padded rows y+half (tap ti adds rows, tj adds cols via soff)
  const short* xh0 = xd + ((size_t)(n * PADW + y) * PADW + row0) * C_IN + part * 8;
  const short* xh1 = xh0 + (size_t)PADW * C_IN;

  f32x4 acc[4][8] = {};

  auto stage = [&](int kt) {
    const int tap = kt >> 2;
    const int cc = kt & 3;
    const int ti = tap / 3;             // uniform scalar math
    const int tj = tap - ti * 3;
    const int wo = kt << 5;                               // shorts
    const int xo = (ti * PADW + tj) * C_IN + (cc << 5);   // shorts, uniform
    short* lb = lds + ((kt & 1) ? 12288 : 0) + tid * 8;
    async_load16(wg0 + wo, lb);                      // Ws o 0..63
    async_load16(wg1 + wo, lb + 2048);               // Ws o 64..127
    async_load16(xh0 + xo, lb + 4096);               // Xs px 0..63   (row y)
    async_load16(xh0 + 64 * C_IN + xo, lb + 6144);   // Xs px 64..127
    async_load16(xh1 + xo, lb + 8192);               // Xs px 128..191 (row y+1)
    async_load16(xh1 + 64 * C_IN + xo, lb + 10240);  // Xs px 192..255
  };

  stage(0);   // prologue

#pragma unroll 4
  for (int kt = 0; kt < 36; ++kt) {
    __syncthreads();   // vmcnt(0) drain: loads(kt) complete; reads(kt-1) done

    if (kt + 1 < 36) stage(kt + 1);

    const short* Ws = lds + ((kt & 1) ? 12288 : 0);
    const short* Xs = Ws + 4096;

    short8 a[4], b[8];
#pragma unroll
    for (int t = 0; t < 4; ++t)
      a[t] = *(const short8*)(Ws + (((wm << 6) + (t << 4) + ln) << 5) + (q << 3));
#pragma unroll
    for (int u = 0; u < 8; ++u)
      b[u] = *(const short8*)(Xs + (((wn << 7) + (u << 4) + ln) << 5) + (q << 3));
#pragma unroll
    for (int t = 0; t < 4; ++t)
#pragma unroll
      for (int u = 0; u < 8; ++u)
        acc[t][u] =
            __builtin_amdgcn_mfma_f32_16x16x32_bf16(a[t], b[u], acc[t][u], 0, 0, 0);
  }

  // epilogue: D layout col=lane&15 (pixel), row=q*4+r (o)
#pragma unroll
  for (int t = 0; t < 4; ++t) {
    const int ob = o0 + (wm << 6) + (t << 4) + (q << 2);
#pragma unroll
    for (int u = 0; u < 8; ++u) {
      const int xcol = (u << 4) + ln;           // 0..127
      const int yrow = y + wn;
#pragma unroll
      for (int r = 0; r < 4; ++r) {
        const int o = ob + r;
        out[(((size_t)n * O_OUT + o) * HW + yrow) * HW + xcol] =
            acc[t][u][r] + bias[o];
      }
    }
  }
}

// ---- fallback (only if ws_size is too small): naive direct conv ------------
__global__ void conv_naive(const float* __restrict__ x,
                           const float* __restrict__ depth,
                           const float* __restrict__ w,
                           const float* __restrict__ bias,
                           float* __restrict__ out) {
  const int gid = blockIdx.x * 256 + threadIdx.x;
  if (gid >= NB * O_OUT * HW * HW) return;
  const int xc = gid & 127;
  const int y = (gid >> 7) & 127;
  const int o = (gid >> 14) & 255;
  const int n = gid >> 22;
  float s = bias[o];
  for (int c = 0; c < C_IN; ++c)
    for (int i = 0; i < 3; ++i) {
      const int yy = y + i - 1;
      if (yy < 0 || yy >= HW) continue;
      for (int j = 0; j < 3; ++j) {
        const int xx = xc + j - 1;
        if (xx < 0 || xx >= HW) continue;
        s += w[((o * C_IN + c) * 3 + i) * 3 + j] *
             x[(((size_t)n * C_IN + c) * HW + yy) * HW + xx] *
             depth[((size_t)n * HW + yy) * HW + xx];
      }
    }
  out[gid] = s;
}

extern "C" void kernel_launch(void* const* d_in, const int* in_sizes, int n_in,
                              void* d_out, int out_size, void* d_ws, size_t ws_size,
                              hipStream_t stream) {
  const float* x = (const float*)d_in[0];
  const float* depth = (const float*)d_in[1];
  // d_in[2] = camera_params (unused by reference)
  const float* weight = (const float*)d_in[3];
  const float* bias = (const float*)d_in[4];
  float* out = (float*)d_out;

  const size_t need = XD_BYTES + WT_BYTES;
  if (ws_size < need) {
    conv_naive<<<(NB * O_OUT * HW * HW + 255) / 256, 256, 0, stream>>>(
        x, depth, weight, bias, out);
    return;
  }

  short* xd = (short*)d_ws;
  short* wt = (short*)((char*)d_ws + XD_BYTES);

  prep_xd<<<NB * HW + NB, 256, 0, stream>>>(x, depth, xd);
  prep_wt<<<(int)((WT_ELEMS + 255) / 256), 256, 0, stream>>>(weight, wt);
  conv_mfma<<<dim3(NB * HW / 2, 2), 256, 0, stream>>>(xd, wt, bias, out);
}

// Round 4
// 136.763 us; speedup vs baseline: 1.2662x; 1.0227x over previous
//
#include <hip/hip_runtime.h>
#include <stdint.h>

// DepthAwareConv2d: out = conv2d(x * depth, weight, pad=1) + bias
// (depth is channel-independent, so the depth-modulated im2col GEMM factors
//  into a plain 3x3 conv of xd = x*depth).
//
// R4: (a) conv K-loop prefetch distance 2 for X (triple-buffered) / 1 for W
//     (double-buffered; wt is L2-resident) -> vmcnt(0) drain at each barrier
//     waits on loads with >=2 full iterations of cover (xd L2-miss latency
//     ~600-900 cyc < ~2x770 cyc compute);  64 KB LDS exactly.
//     (b) all prep fused into ONE dispatch (rows + halo + weights), with
//     conflict-free c-major LDS transpose (bank = c + lane).

#define C_IN 128
#define O_OUT 256
#define HW 128
#define NB 4
#define PADW 130

#define XD_ELEMS ((size_t)NB * PADW * PADW * C_IN)
#define XD_BYTES (XD_ELEMS * 2)          // 17,305,600 B
#define WT_ELEMS ((size_t)O_OUT * C_IN * 9)
#define WT_BYTES (WT_ELEMS * 2)          // 589,824 B

typedef __attribute__((ext_vector_type(8))) short short8;  // 8 bf16 (4 VGPRs)
typedef __attribute__((ext_vector_type(4))) float f32x4;
typedef __attribute__((ext_vector_type(2))) float f32x2;
typedef __attribute__((ext_vector_type(4))) unsigned uint4v;

__device__ __forceinline__ unsigned f2bf_bits(float f) {
  unsigned u = __builtin_bit_cast(unsigned, f);
  return (u + 0x7fffu + ((u >> 16) & 1u)) >> 16;   // RNE, inputs finite
}

__device__ __forceinline__ void async_load16(const void* g, void* l) {
  __builtin_amdgcn_global_load_lds(
      (__attribute__((address_space(1))) void*)g,
      (__attribute__((address_space(3))) void*)l, 16, 0, 0);
}

// ---- prep (single dispatch): xd rows + halo + weight relayout --------------
// Blocks 0..511   : one (n,y) row. Phase 1: coalesced float2 reads of x,
//                   scale by depth, dword write into c-major LDS (stride 130
//                   shorts; bank = c+lane, conflict-free). Phase 2: coalesced
//                   NHWC dword writes (2x ds_read_u16 + pack per dword).
// Blocks 512..515 : zero halo rows 0 and 129 of image n.
// Blocks 516..579 : wt[o][tap*128+c] = bf16(weight[o,c,ti,tj]), 4608 elems ea.
__global__ __launch_bounds__(256) void prep_all(const float* __restrict__ x,
                                                const float* __restrict__ depth,
                                                const float* __restrict__ w,
                                                short* __restrict__ xd,
                                                short* __restrict__ wt) {
  const int R = blockIdx.x;

  if (R >= NB * HW + NB) {                  // ---- weight blocks
    int gid = (R - (NB * HW + NB)) * 4608 + threadIdx.x;   // 64 * 4608 = 294912
#pragma unroll
    for (int i = 0; i < 18; ++i, gid += 256) {
      const int c = gid & 127;
      const int tap = (gid >> 7) % 9;
      const int o = gid / 1152;
      wt[gid] = (short)f2bf_bits(w[((size_t)o * C_IN + c) * 9 + tap]);
    }
    return;
  }

  if (R >= NB * HW) {                       // ---- halo-row zero blocks
    const int n = R - NB * HW;
    uint4v* base0 = (uint4v*)(xd + (size_t)n * PADW * PADW * C_IN);
    uint4v* base1 = (uint4v*)(xd + ((size_t)n * PADW + (PADW - 1)) * PADW * C_IN);
    const uint4v z = {0u, 0u, 0u, 0u};
    const int per_row = PADW * C_IN * 2 / 16;   // 2080 uint4 per padded row
    for (int i = threadIdx.x; i < per_row; i += 256) {
      base0[i] = z;
      base1[i] = z;
    }
    return;
  }

  // ---- row-transform blocks
  __shared__ short s[C_IN * PADW];   // c-major: s[c*130 + px]

  const int n = R >> 7, y = R & 127;
  const int tid = threadIdx.x;
  const int lane = tid & 63;
  const int wave = tid >> 6;

  // zero the two edge pixels of this padded row (x=0 and x=129)
  {
    unsigned* row = (unsigned*)(xd + ((size_t)(n * PADW + y + 1) * PADW) * C_IN);
    if (tid < 64) row[tid] = 0u;                              // pixel 0
    else if (tid < 128) row[(size_t)(PADW - 1) * 64 + (tid - 64)] = 0u;  // pixel 129
  }

  // phase 1: read x (float2, coalesced), scale, dword-write to LDS (c-major)
  const f32x2 d2 = *(const f32x2*)(depth + ((size_t)n * HW + y) * HW + 2 * lane);
  const float* xrow = x + (((size_t)n * C_IN) * HW + y) * HW + 2 * lane;
  unsigned* s32 = (unsigned*)s;
#pragma unroll 8
  for (int ci = 0; ci < 32; ++ci) {
    const int c = ci * 4 + wave;
    const f32x2 v = *(const f32x2*)(xrow + (size_t)c * HW * HW);
    s32[c * 65 + lane] = f2bf_bits(v.x * d2.x) | (f2bf_bits(v.y * d2.y) << 16);
  }
  __syncthreads();

  // phase 2: coalesced NHWC write (pixels 1..128 of the padded row)
  const unsigned short* s16 = (const unsigned short*)s;
  unsigned* orow = (unsigned*)(xd + ((size_t)(n * PADW + y + 1) * PADW + 1) * C_IN);
#pragma unroll 8
  for (int i = 0; i < 32; ++i) {
    const int flat = tid + i * 256;      // 0..8191 dwords
    const int px = flat >> 6, cp = flat & 63;
    const unsigned lo = s16[(2 * cp) * PADW + px];
    const unsigned hi = s16[(2 * cp + 1) * PADW + px];
    orow[flat] = lo | (hi << 16);
  }
}

// ---- main MFMA implicit-GEMM conv ------------------------------------------
// Block: 256 threads (4 waves, 2x2), tile 128(o) x 256(px = 2 image rows).
// Wave tile 64(o) x 128(px): acc 4x8. K = 1152, BK=32, 36 steps.
// LDS 64 KB: Ws double-buffered (2 x 8 KB), Xs triple-buffered (3 x 16 KB).
// One barrier/iter. Prefetch: W(kt+1), X(kt+2) issued after barrier(kt) ->
// at barrier(kt) the vmcnt(0) drain waits on W with 1 iter of cover (L2-hot)
// and X with 2 iters of cover (survives xd L2-miss latency).
__global__ __launch_bounds__(256, 2) void conv_mfma(
    const short* __restrict__ xd, const short* __restrict__ wt,
    const float* __restrict__ bias, float* __restrict__ out) {
  __shared__ short lds[32768];   // Ws: [0,8192) x2; Xs: [8192,32768) x3

  const int tid = threadIdx.x;
  const int bx = blockIdx.x;            // n*64 + ypair
  const int n = bx >> 6;
  const int y = (bx & 63) << 1;         // first of two output rows
  const int o0 = blockIdx.y << 7;
  const int lane = tid & 63;
  const int wave = tid >> 6;
  const int wm = wave & 1, wn = wave >> 1;
  const int ln = lane & 15, q = lane >> 4;

  // staging: slot tid = (row0 = tid>>2, part = tid&3), 16 B per slot
  const int row0 = tid >> 2;            // 0..63
  const int part = tid & 3;

  const short* wg0 = wt + (size_t)(o0 + row0) * 1152 + part * 8;
  const short* wg1 = wg0 + (size_t)64 * 1152;
  const short* xh0 = xd + ((size_t)(n * PADW + y) * PADW + row0) * C_IN + part * 8;
  const short* xh1 = xh0 + (size_t)PADW * C_IN;

  f32x4 acc[4][8] = {};

  auto stageW = [&](int kt) {
    short* lb = lds + ((kt & 1) << 12) + tid * 8;
    const int wo = kt << 5;
    async_load16(wg0 + wo, lb);                      // o 0..63
    async_load16(wg1 + wo, lb + 2048);               // o 64..127
  };
  auto stageX = [&](int kt) {
    const int tap = kt >> 2;
    const int cc = kt & 3;
    const int ti = tap / 3;             // uniform scalar math
    const int tj = tap - ti * 3;
    const int xo = (ti * PADW + tj) * C_IN + (cc << 5);   // shorts, uniform
    short* lb = lds + 8192 + (kt % 3) * 8192 + tid * 8;
    async_load16(xh0 + xo, lb);                      // px 0..63   (row y)
    async_load16(xh0 + 64 * C_IN + xo, lb + 2048);   // px 64..127
    async_load16(xh1 + xo, lb + 4096);               // px 128..191 (row y+1)
    async_load16(xh1 + 64 * C_IN + xo, lb + 6144);   // px 192..255
  };

  stageW(0);
  stageX(0);
  stageX(1);

#pragma unroll 6
  for (int kt = 0; kt < 36; ++kt) {
    __syncthreads();   // vmcnt(0) drain: W(kt) 1-iter cover, X(kt) 2-iter cover

    if (kt + 1 < 36) stageW(kt + 1);
    if (kt + 2 < 36) stageX(kt + 2);

    const short* Ws = lds + ((kt & 1) << 12);
    const short* Xs = lds + 8192 + (kt % 3) * 8192;

    short8 a[4], b[8];
#pragma unroll
    for (int t = 0; t < 4; ++t)
      a[t] = *(const short8*)(Ws + (((wm << 6) + (t << 4) + ln) << 5) + (q << 3));
#pragma unroll
    for (int u = 0; u < 8; ++u)
      b[u] = *(const short8*)(Xs + (((wn << 7) + (u << 4) + ln) << 5) + (q << 3));
#pragma unroll
    for (int t = 0; t < 4; ++t)
#pragma unroll
      for (int u = 0; u < 8; ++u)
        acc[t][u] =
            __builtin_amdgcn_mfma_f32_16x16x32_bf16(a[t], b[u], acc[t][u], 0, 0, 0);
  }

  // epilogue: D layout col=lane&15 (pixel), row=q*4+r (o)
#pragma unroll
  for (int t = 0; t < 4; ++t) {
    const int ob = o0 + (wm << 6) + (t << 4) + (q << 2);
#pragma unroll
    for (int u = 0; u < 8; ++u) {
      const int xcol = (u << 4) + ln;           // 0..127
      const int yrow = y + wn;
#pragma unroll
      for (int r = 0; r < 4; ++r) {
        const int o = ob + r;
        out[(((size_t)n * O_OUT + o) * HW + yrow) * HW + xcol] =
            acc[t][u][r] + bias[o];
      }
    }
  }
}

// ---- fallback (only if ws_size is too small): naive direct conv ------------
__global__ void conv_naive(const float* __restrict__ x,
                           const float* __restrict__ depth,
                           const float* __restrict__ w,
                           const float* __restrict__ bias,
                           float* __restrict__ out) {
  const int gid = blockIdx.x * 256 + threadIdx.x;
  if (gid >= NB * O_OUT * HW * HW) return;
  const int xc = gid & 127;
  const int y = (gid >> 7) & 127;
  const int o = (gid >> 14) & 255;
  const int n = gid >> 22;
  float s = bias[o];
  for (int c = 0; c < C_IN; ++c)
    for (int i = 0; i < 3; ++i) {
      const int yy = y + i - 1;
      if (yy < 0 || yy >= HW) continue;
      for (int j = 0; j < 3; ++j) {
        const int xx = xc + j - 1;
        if (xx < 0 || xx >= HW) continue;
        s += w[((o * C_IN + c) * 3 + i) * 3 + j] *
             x[(((size_t)n * C_IN + c) * HW + yy) * HW + xx] *
             depth[((size_t)n * HW + yy) * HW + xx];
      }
    }
  out[gid] = s;
}

extern "C" void kernel_launch(void* const* d_in, const int* in_sizes, int n_in,
                              void* d_out, int out_size, void* d_ws, size_t ws_size,
                              hipStream_t stream) {
  const float* x = (const float*)d_in[0];
  const float* depth = (const float*)d_in[1];
  // d_in[2] = camera_params (unused by reference)
  const float* weight = (const float*)d_in[3];
  const float* bias = (const float*)d_in[4];
  float* out = (float*)d_out;

  const size_t need = XD_BYTES + WT_BYTES;
  if (ws_size < need) {
    conv_naive<<<(NB * O_OUT * HW * HW + 255) / 256, 256, 0, stream>>>(
        x, depth, weight, bias, out);
    return;
  }

  short* xd = (short*)d_ws;
  short* wt = (short*)((char*)d_ws + XD_BYTES);

  prep_all<<<NB * HW + NB + 64, 256, 0, stream>>>(x, depth, weight, xd, wt);
  conv_mfma<<<dim3(NB * HW / 2, 2), 256, 0, stream>>>(xd, wt, bias, out);
}

// Round 6
// 134.838 us; speedup vs baseline: 1.2843x; 1.0143x over previous
//
#include <hip/hip_runtime.h>
#include <stdint.h>

// DepthAwareConv2d: out = conv2d(x * depth, weight, pad=1) + bias
// (depth is channel-independent, so the depth-modulated im2col GEMM factors
//  into a plain 3x3 conv of xd = x*depth).
//
// R6 = R5 with the prep/conv K-ordering mismatch fixed.
//  - W bypasses LDS: prep writes wt2 in exact MFMA A-fragment order, slot
//    s = cc*9 + tap  (MUST match conv's cc-outer/tap-inner K order — R5 wrote
//    tap-major slots -> scrambled weights, absmax 9.66).
//  - X loop cc-outer / tap-inner: one 4row x 130px x 32ch strip (33,280 B)
//    staged per cc-phase; all 9 taps read it at static LDS offsets.
//    Barriers: 8 total (2 per cc-phase); the 9-tap inner loop is barrier-free
//    so MFMA interleaves with a-frag global loads under fine-grained waitcnts.

#define C_IN 128
#define O_OUT 256
#define HW 128
#define NB 4
#define PADW 130

#define XD_ELEMS ((size_t)NB * PADW * PADW * C_IN)
#define XD_BYTES (XD_ELEMS * 2)          // 17,305,600 B
#define WT_ELEMS ((size_t)O_OUT * C_IN * 9)
#define WT_BYTES (WT_ELEMS * 2)          // 589,824 B

typedef __attribute__((ext_vector_type(8))) short short8;  // 8 bf16 (4 VGPRs)
typedef __attribute__((ext_vector_type(4))) float f32x4;
typedef __attribute__((ext_vector_type(2))) float f32x2;
typedef __attribute__((ext_vector_type(4))) unsigned uint4v;

__device__ __forceinline__ unsigned f2bf_bits(float f) {
  unsigned u = __builtin_bit_cast(unsigned, f);
  return (u + 0x7fffu + ((u >> 16) & 1u)) >> 16;   // RNE, inputs finite
}

__device__ __forceinline__ void async_load16(const void* g, void* l) {
  __builtin_amdgcn_global_load_lds(
      (__attribute__((address_space(1))) void*)g,
      (__attribute__((address_space(3))) void*)l, 16, 0, 0);
}

// ---- prep (single dispatch): xd rows + halo + weight frag-relayout ---------
// Blocks 0..511   : one (n,y) row. Coalesced float2 reads of x, scale by
//                   depth, c-major LDS transpose, coalesced NHWC writes.
// Blocks 512..515 : zero halo rows 0 and 129 of image n.
// Blocks 516..579 : wt2 in MFMA-A-fragment order, K-slot s = cc*9 + tap:
//   gid = o0*147456 + s*4096 + wm*2048 + lane*32 + t*8 + j   (shorts)
//   o = o0*128 + wm*64 + t*16 + (lane&15)
//   cc = s/9; tap = s%9; c = cc*32 + (lane>>4)*8 + j
__global__ __launch_bounds__(256) void prep_all(const float* __restrict__ x,
                                                const float* __restrict__ depth,
                                                const float* __restrict__ w,
                                                short* __restrict__ xd,
                                                short* __restrict__ wt2) {
  const int R = blockIdx.x;

  if (R >= NB * HW + NB) {                  // ---- weight blocks
    int gid = (R - (NB * HW + NB)) * 4608 + threadIdx.x;   // 64 * 4608 = 294912
#pragma unroll
    for (int i = 0; i < 18; ++i, gid += 256) {
      const int j = gid & 7;
      const int t = (gid >> 3) & 3;
      const int lane = (gid >> 5) & 63;
      const int wm = (gid >> 11) & 1;
      const int g2 = gid >> 12;
      const int s = g2 % 36;               // K-slot in conv order: cc*9 + tap
      const int o0 = g2 / 36;
      const int ln = lane & 15, q = lane >> 4;
      const int o = (o0 << 7) + (wm << 6) + (t << 4) + ln;
      const int cc = s / 9;
      const int tap = s % 9;
      const int c = (cc << 5) + (q << 3) + j;
      wt2[gid] = (short)f2bf_bits(w[((size_t)o * C_IN + c) * 9 + tap]);
    }
    return;
  }

  if (R >= NB * HW) {                       // ---- halo-row zero blocks
    const int n = R - NB * HW;
    uint4v* base0 = (uint4v*)(xd + (size_t)n * PADW * PADW * C_IN);
    uint4v* base1 = (uint4v*)(xd + ((size_t)n * PADW + (PADW - 1)) * PADW * C_IN);
    const uint4v z = {0u, 0u, 0u, 0u};
    const int per_row = PADW * C_IN * 2 / 16;   // 2080 uint4 per padded row
    for (int i = threadIdx.x; i < per_row; i += 256) {
      base0[i] = z;
      base1[i] = z;
    }
    return;
  }

  // ---- row-transform blocks
  __shared__ short s[C_IN * PADW];   // c-major: s[c*130 + px]

  const int n = R >> 7, y = R & 127;
  const int tid = threadIdx.x;
  const int lane = tid & 63;
  const int wave = tid >> 6;

  // zero the two edge pixels of this padded row (x=0 and x=129)
  {
    unsigned* row = (unsigned*)(xd + ((size_t)(n * PADW + y + 1) * PADW) * C_IN);
    if (tid < 64) row[tid] = 0u;                              // pixel 0
    else if (tid < 128) row[(size_t)(PADW - 1) * 64 + (tid - 64)] = 0u;  // pixel 129
  }

  // phase 1: read x (float2, coalesced), scale, dword-write to LDS (c-major)
  const f32x2 d2 = *(const f32x2*)(depth + ((size_t)n * HW + y) * HW + 2 * lane);
  const float* xrow = x + (((size_t)n * C_IN) * HW + y) * HW + 2 * lane;
  unsigned* s32 = (unsigned*)s;
#pragma unroll 8
  for (int ci = 0; ci < 32; ++ci) {
    const int c = ci * 4 + wave;
    const f32x2 v = *(const f32x2*)(xrow + (size_t)c * HW * HW);
    s32[c * 65 + lane] = f2bf_bits(v.x * d2.x) | (f2bf_bits(v.y * d2.y) << 16);
  }
  __syncthreads();

  // phase 2: coalesced NHWC write (pixels 1..128 of the padded row)
  const unsigned short* s16 = (const unsigned short*)s;
  unsigned* orow = (unsigned*)(xd + ((size_t)(n * PADW + y + 1) * PADW + 1) * C_IN);
#pragma unroll 8
  for (int i = 0; i < 32; ++i) {
    const int flat = tid + i * 256;      // 0..8191 dwords
    const int px = flat >> 6, cp = flat & 63;
    const unsigned lo = s16[(2 * cp) * PADW + px];
    const unsigned hi = s16[(2 * cp + 1) * PADW + px];
    orow[flat] = lo | (hi << 16);
  }
}

// ---- main MFMA implicit-GEMM conv ------------------------------------------
// Block: 256 threads (4 waves, 2x2), tile 128(o) x 256(px = 2 output rows).
// Wave tile 64(o) x 128(px): acc 4x8. K = 1152 as (cc 0..3) x (tap 0..8).
// Per cc-phase: stage 4row x 130px x 32ch strip (33,280 B) into the single
// LDS buffer; 9 barrier-free tap steps read it at static ds offsets while
// a-frags stream from global (wt2, fragment-major) with ping-pong prefetch.
__global__ __launch_bounds__(256, 2) void conv_mfma(
    const short* __restrict__ xd, const short* __restrict__ wt2,
    const float* __restrict__ bias, float* __restrict__ out) {
  __shared__ short xbuf[16640];   // [px_strip 520][32 ch]  (33,280 B)

  const int tid = threadIdx.x;
  const int bx = blockIdx.x;            // n*64 + ypair
  const int n = bx >> 6;
  const int y = (bx & 63) << 1;         // first of two output rows
  const int o0b = blockIdx.y;           // o tile (x128)
  const int lane = tid & 63;
  const int wave = tid >> 6;
  const int wm = wave & 1, wn = wave >> 1;
  const int ln = lane & 15, q = lane >> 4;

  // W fragment stream base (shorts): wt2 + o0*147456 + wm*2048 + lane*32
  const short* wbase =
      wt2 + (size_t)o0b * 147456 + (wm << 11) + (lane << 5);

  // X strip staging: strip = padded rows y..y+3, px 0..129, chunk f=0..2079
  // src(f) = strip_base + (f>>2)*128 + cc*32 + (f&3)*8 ; lds(f) = f*8
  const short* xsrc0 = xd + (size_t)(n * PADW + y) * PADW * C_IN +
                       (tid >> 2) * C_IN + (tid & 3) * 8;
  short* xdst0 = xbuf + tid * 8;

  f32x4 acc[4][8] = {};
  short8 areg[2][4];

  auto loadA = [&](int s, int p) {
#pragma unroll
    for (int t = 0; t < 4; ++t)
      areg[p][t] = *(const short8*)(wbase + (size_t)s * 4096 + t * 8);
  };
  auto stageX = [&](int cc) {
    const short* sp = xsrc0 + (cc << 5);
#pragma unroll
    for (int j = 0; j < 8; ++j)
      async_load16(sp + j * 8192, xdst0 + j * 2048);
    if (tid < 32) async_load16(sp + 8 * 8192, xdst0 + 8 * 2048);  // tail 32 chunks
  };

  loadA(0, 0);
  stageX(0);
  __syncthreads();   // vmcnt(0) drain: xbuf(cc=0) ready

#pragma unroll
  for (int cc = 0; cc < 4; ++cc) {
#pragma unroll
    for (int tap = 0; tap < 9; ++tap) {
      const int s = cc * 9 + tap;
      if (s + 1 < 36) loadA(s + 1, (s + 1) & 1);   // prefetch next a-frags

      const int ti = tap / 3, tj = tap % 3;        // static under unroll
      const int rbase = (wn + ti) * 130 + tj;      // strip row + col shift

      short8 b[8];
#pragma unroll
      for (int u = 0; u < 8; ++u)
        b[u] = *(const short8*)(xbuf + (rbase + (u << 4) + ln) * 32 + (q << 3));
#pragma unroll
      for (int t = 0; t < 4; ++t)
#pragma unroll
        for (int u = 0; u < 8; ++u)
          acc[t][u] = __builtin_amdgcn_mfma_f32_16x16x32_bf16(
              areg[s & 1][t], b[u], acc[t][u], 0, 0, 0);
    }
    if (cc + 1 < 4) {
      __syncthreads();       // all waves done reading xbuf(cc)
      stageX(cc + 1);
      __syncthreads();       // drain: xbuf(cc+1) ready
    }
  }

  // epilogue: D layout col=lane&15 (pixel), row=q*4+r (o)
#pragma unroll
  for (int t = 0; t < 4; ++t) {
    const int ob = (o0b << 7) + (wm << 6) + (t << 4) + (q << 2);
#pragma unroll
    for (int u = 0; u < 8; ++u) {
      const int xcol = (u << 4) + ln;           // 0..127
      const int yrow = y + wn;
#pragma unroll
      for (int r = 0; r < 4; ++r) {
        const int o = ob + r;
        out[(((size_t)n * O_OUT + o) * HW + yrow) * HW + xcol] =
            acc[t][u][r] + bias[o];
      }
    }
  }
}

// ---- fallback (only if ws_size is too small): naive direct conv ------------
__global__ void conv_naive(const float* __restrict__ x,
                           const float* __restrict__ depth,
                           const float* __restrict__ w,
                           const float* __restrict__ bias,
                           float* __restrict__ out) {
  const int gid = blockIdx.x * 256 + threadIdx.x;
  if (gid >= NB * O_OUT * HW * HW) return;
  const int xc = gid & 127;
  const int y = (gid >> 7) & 127;
  const int o = (gid >> 14) & 255;
  const int n = gid >> 22;
  float s = bias[o];
  for (int c = 0; c < C_IN; ++c)
    for (int i = 0; i < 3; ++i) {
      const int yy = y + i - 1;
      if (yy < 0 || yy >= HW) continue;
      for (int j = 0; j < 3; ++j) {
        const int xx = xc + j - 1;
        if (xx < 0 || xx >= HW) continue;
        s += w[((o * C_IN + c) * 3 + i) * 3 + j] *
             x[(((size_t)n * C_IN + c) * HW + yy) * HW + xx] *
             depth[((size_t)n * HW + yy) * HW + xx];
      }
    }
  out[gid] = s;
}

extern "C" void kernel_launch(void* const* d_in, const int* in_sizes, int n_in,
                              void* d_out, int out_size, void* d_ws, size_t ws_size,
                              hipStream_t stream) {
  const float* x = (const float*)d_in[0];
  const float* depth = (const float*)d_in[1];
  // d_in[2] = camera_params (unused by reference)
  const float* weight = (const float*)d_in[3];
  const float* bias = (const float*)d_in[4];
  float* out = (float*)d_out;

  const size_t need = XD_BYTES + WT_BYTES;
  if (ws_size < need) {
    conv_naive<<<(NB * O_OUT * HW * HW + 255) / 256, 256, 0, stream>>>(
        x, depth, weight, bias, out);
    return;
  }

  short* xd = (short*)d_ws;
  short* wt2 = (short*)((char*)d_ws + XD_BYTES);

  prep_all<<<NB * HW + NB + 64, 256, 0, stream>>>(x, depth, weight, xd, wt2);
  conv_mfma<<<dim3(NB * HW / 2, 2), 256, 0, stream>>>(xd, wt2, bias, out);
}